// Round 1
// baseline (199.291 us; speedup 1.0000x reference)
//
#include <hip/hip_runtime.h>
#include <cstdint>
#include <cstddef>

// DigitCapsules routing: B=256, R=1152, C=10, IC=8, OC=16, 3 iters.
// Pipeline (6 launches, deterministic, no atomics):
//   1. caps_u:      u[b][c][r][o] = sum_i x[b,r,i]*W[r,c,i,o]  (bf16, 94 MB)
//   2. caps_route:  s1 = 0.1*sum_r u     -> v1 = squash -> vsum := v1
//   3. caps_cc:     cc = softmax_c(u . vsum)          (logits linear in v!)
//   4. caps_route:  s2 = sum_r cc*u -> v2 -> vsum += v2
//   5. caps_cc:     cc = softmax_c(u . vsum)
//   6. caps_route:  s3 -> v3 -> d_out
#define NB 256
#define NR 1152
#define NC 10
#define NI 8
#define NO 16

// pack two fp32 into one uint32 of bf16s (round-to-nearest-even)
static __device__ __forceinline__ uint32_t bf16_pack2(float lo, float hi) {
    uint32_t vl = __float_as_uint(lo);
    vl = vl + 0x7FFFu + ((vl >> 16) & 1u);
    uint32_t vh = __float_as_uint(hi);
    vh = vh + 0x7FFFu + ((vh >> 16) & 1u);
    return (vl >> 16) | (vh & 0xFFFF0000u);
}

// -------------------------------------------------------------------------
// u-compute: thread owns one (c,r), loops 8 batches reusing W in registers.
// grid: 32 b-groups * 10 c * 1152 r / 256 = 1440 blocks
__global__ __launch_bounds__(256) void caps_u_kernel(
    const float* __restrict__ x, const float* __restrict__ W,
    uint32_t* __restrict__ u)
{
    const int ft  = blockIdx.x * 256 + threadIdx.x;   // [0, 368640)
    const int bg  = ft / (NC * NR);                   // [0, 32)
    const int rem = ft - bg * (NC * NR);
    const int c   = rem / NR;
    const int r   = rem - c * NR;

    // W[r][c][i][o] : 128 contiguous floats -> 32 float4 in registers
    const float4* wp = (const float4*)(W + (r * NC + c) * (NI * NO));
    float4 w[32];
#pragma unroll
    for (int k = 0; k < 32; ++k) w[k] = wp[k];

    for (int bi = 0; bi < 8; ++bi) {
        const int b = bg * 8 + bi;
        const float4* xp = (const float4*)(x + (b * NR + r) * NI);
        const float4 xa = xp[0];
        const float4 xb = xp[1];
        const float xi[8] = {xa.x, xa.y, xa.z, xa.w, xb.x, xb.y, xb.z, xb.w};
        float4 a0 = {0,0,0,0}, a1 = {0,0,0,0}, a2 = {0,0,0,0}, a3 = {0,0,0,0};
#pragma unroll
        for (int i = 0; i < 8; ++i) {
            const float xv = xi[i];
            const float4 w0 = w[i*4+0], w1 = w[i*4+1], w2 = w[i*4+2], w3 = w[i*4+3];
            a0.x += xv*w0.x; a0.y += xv*w0.y; a0.z += xv*w0.z; a0.w += xv*w0.w;
            a1.x += xv*w1.x; a1.y += xv*w1.y; a1.z += xv*w1.z; a1.w += xv*w1.w;
            a2.x += xv*w2.x; a2.y += xv*w2.y; a2.z += xv*w2.z; a2.w += xv*w2.w;
            a3.x += xv*w3.x; a3.y += xv*w3.y; a3.z += xv*w3.z; a3.w += xv*w3.w;
        }
        // row layout: word wd holds elems o=2wd (lo16), o=2wd+1 (hi16)
        uint4 s0, s1;
        s0.x = bf16_pack2(a0.x, a0.y); s0.y = bf16_pack2(a0.z, a0.w);
        s0.z = bf16_pack2(a1.x, a1.y); s0.w = bf16_pack2(a1.z, a1.w);
        s1.x = bf16_pack2(a2.x, a2.y); s1.y = bf16_pack2(a2.z, a2.w);
        s1.z = bf16_pack2(a3.x, a3.y); s1.w = bf16_pack2(a3.z, a3.w);
        uint4* up = (uint4*)(u + ((b * NC + c) * NR + r) * 8);
        up[0] = s0;
        up[1] = s1;
    }
}

// -------------------------------------------------------------------------
// coupling coefficients: cc[b][c][r] = softmax_c( u[b,c,r,:] . vsum[b,c,:] )
// grid: 256 b * 5 r-chunks = 1280 blocks (last chunk partially active)
__global__ __launch_bounds__(256) void caps_cc_kernel(
    const uint32_t* __restrict__ u, const float* __restrict__ vsum,
    float* __restrict__ cc)
{
    const int b     = blockIdx.x / 5;
    const int chunk = blockIdx.x - b * 5;
    __shared__ float vs[NC * NO];
    if (threadIdx.x < NC * NO) vs[threadIdx.x] = vsum[b * (NC * NO) + threadIdx.x];
    __syncthreads();
    const int r = chunk * 256 + threadIdx.x;
    if (r >= NR) return;

    float lg[NC];
#pragma unroll
    for (int c = 0; c < NC; ++c) {
        const uint4* up = (const uint4*)(u + ((b * NC + c) * NR + r) * 8);
        const uint4 q0 = up[0];
        const uint4 q1 = up[1];
        const uint32_t wd[8] = {q0.x, q0.y, q0.z, q0.w, q1.x, q1.y, q1.z, q1.w};
        float d = 0.f;
#pragma unroll
        for (int k = 0; k < 8; ++k) {
            d += __uint_as_float(wd[k] << 16)        * vs[c * NO + 2*k]
               + __uint_as_float(wd[k] & 0xFFFF0000u) * vs[c * NO + 2*k + 1];
        }
        lg[c] = d;
    }
    float m = lg[0];
#pragma unroll
    for (int c = 1; c < NC; ++c) m = fmaxf(m, lg[c]);
    float e[NC];
    float ssum = 0.f;
#pragma unroll
    for (int c = 0; c < NC; ++c) { e[c] = __expf(lg[c] - m); ssum += e[c]; }
    const float inv = 1.f / ssum;
#pragma unroll
    for (int c = 0; c < NC; ++c) cc[(b * NC + c) * NR + r] = e[c] * inv;
}

// -------------------------------------------------------------------------
// s-reduction + squash + vsum bookkeeping.
// One block per (b,c); 256 threads = 64 r-groups x 4 o-quads; 18 r-iters.
// mode 0: vsum  = v   (pass 1, cc==nullptr -> uniform 0.1)
// mode 1: vsum += v   (pass 2)
// mode 2: out   = v   (pass 3)
__global__ __launch_bounds__(256) void caps_route_kernel(
    const uint32_t* __restrict__ u, const float* __restrict__ cc,
    float* __restrict__ vsum, float* __restrict__ out, const int mode)
{
    const int b = blockIdx.x / NC;
    const int c = blockIdx.x - b * NC;
    __shared__ float  ccl[NR];
    __shared__ float4 red[256];
    if (cc != nullptr) {
        for (int k = threadIdx.x; k < NR; k += 256)
            ccl[k] = cc[(b * NC + c) * NR + k];
    } else {
        for (int k = threadIdx.x; k < NR; k += 256) ccl[k] = 0.1f;
    }
    __syncthreads();

    const int og = threadIdx.x & 3;   // o-quad: o = og*4 .. og*4+3
    const int rg = threadIdx.x >> 2;  // [0,64)
    float4 acc = {0,0,0,0};
    const uint2* ub = (const uint2*)(u + (b * NC + c) * NR * 8);
#pragma unroll
    for (int k = 0; k < 18; ++k) {     // 18*64 = 1152
        const int r = k * 64 + rg;
        const uint2 q = ub[r * 4 + og];
        const float wv = ccl[r];
        acc.x += wv * __uint_as_float(q.x << 16);
        acc.y += wv * __uint_as_float(q.x & 0xFFFF0000u);
        acc.z += wv * __uint_as_float(q.y << 16);
        acc.w += wv * __uint_as_float(q.y & 0xFFFF0000u);
    }
    red[threadIdx.x] = acc;
    __syncthreads();
    for (int off = 128; off >= 4; off >>= 1) {   // reduce over rg
        if (threadIdx.x < off) {
            float4 a = red[threadIdx.x];
            const float4 t = red[threadIdx.x + off];
            a.x += t.x; a.y += t.y; a.z += t.z; a.w += t.w;
            red[threadIdx.x] = a;
        }
        __syncthreads();
    }
    if (threadIdx.x == 0) {
        float sv[16];
#pragma unroll
        for (int wq = 0; wq < 4; ++wq) {
            const float4 q = red[wq];
            sv[wq*4+0] = q.x; sv[wq*4+1] = q.y; sv[wq*4+2] = q.z; sv[wq*4+3] = q.w;
        }
        float n2 = 0.f;
#pragma unroll
        for (int o = 0; o < 16; ++o) n2 += sv[o] * sv[o];
        const float nrm   = sqrtf(n2);
        const float scale = n2 / (1.f + n2) / (nrm + 1e-8f);
        if (mode == 0) {
            float* dst = vsum + (b * NC + c) * NO;
#pragma unroll
            for (int o = 0; o < NO; ++o) dst[o] = scale * sv[o];
        } else if (mode == 1) {
            float* dst = vsum + (b * NC + c) * NO;
#pragma unroll
            for (int o = 0; o < NO; ++o) dst[o] += scale * sv[o];
        } else {
            float* dst = out + (b * NC + c) * NO;
#pragma unroll
            for (int o = 0; o < NO; ++o) dst[o] = scale * sv[o];
        }
    }
}

// -------------------------------------------------------------------------
extern "C" void kernel_launch(void* const* d_in, const int* in_sizes, int n_in,
                              void* d_out, int out_size, void* d_ws, size_t ws_size,
                              hipStream_t stream) {
    const float* x = (const float*)d_in[0];   // [256,1152,8]
    const float* W = (const float*)d_in[1];   // [1,1152,10,8,16]
    float* out = (float*)d_out;               // [256,10,16]

    // workspace carve (needs ~106.4 MB):
    //   u    : bf16 [B][C][R][O]  94,371,840 B (as packed uint32)
    //   cc   : f32  [B][C][R]     11,796,480 B
    //   vsum : f32  [B][C][O]        163,840 B
    uint8_t* ws   = (uint8_t*)d_ws;
    uint32_t* u   = (uint32_t*)ws;
    float*    cc  = (float*)(ws + 94371840u);
    float*    vsm = (float*)(ws + 94371840u + 11796480u);

    caps_u_kernel    <<<1440, 256, 0, stream>>>(x, W, u);
    caps_route_kernel<<<2560, 256, 0, stream>>>(u, nullptr, vsm, nullptr, 0); // s1 -> v1, vsum=v1
    caps_cc_kernel   <<<1280, 256, 0, stream>>>(u, vsm, cc);                  // cc2
    caps_route_kernel<<<2560, 256, 0, stream>>>(u, cc, vsm, nullptr, 1);      // s2 -> v2, vsum+=v2
    caps_cc_kernel   <<<1280, 256, 0, stream>>>(u, vsm, cc);                  // cc3
    caps_route_kernel<<<2560, 256, 0, stream>>>(u, cc, nullptr, out, 2);      // s3 -> v3 -> out
}